// Round 2
// baseline (796.006 us; speedup 1.0000x reference)
//
#include <hip/hip_runtime.h>
#include <stdint.h>
#include <math.h>

typedef float f4 __attribute__((ext_vector_type(4)));

// ---------------- Threefry-2x32 (exact JAX replication) ----------------
static __device__ __forceinline__ uint32_t rotl32(uint32_t x, int r) {
    return (x << r) | (x >> (32 - r));
}

static __device__ __forceinline__ void tf2x32(uint32_t k0, uint32_t k1,
                                              uint32_t& x0, uint32_t& x1) {
    uint32_t ks2 = k0 ^ k1 ^ 0x1BD11BDAu;
    x0 += k0; x1 += k1;
#define TFR(r) { x0 += x1; x1 = rotl32(x1, r); x1 ^= x0; }
    TFR(13) TFR(15) TFR(26) TFR(6)
    x0 += k1;  x1 += ks2 + 1u;
    TFR(17) TFR(29) TFR(16) TFR(24)
    x0 += ks2; x1 += k0 + 2u;
    TFR(13) TFR(15) TFR(26) TFR(6)
    x0 += k0;  x1 += k1 + 3u;
    TFR(17) TFR(29) TFR(16) TFR(24)
    x0 += k1;  x1 += ks2 + 4u;
    TFR(13) TFR(15) TFR(26) TFR(6)
    x0 += ks2; x1 += k0 + 5u;
#undef TFR
}

// jax.random.split(key(42), 3): threefry_2x32((0,42), iota(6)) reshaped (3,2).
// out = [a0,a1,a2,b0,b1,b2] where (a_i,b_i) = cipher(i, i+3)
// k1=(a0,a1)  k2=(a2,b0)  k3=(b1,b2)
struct SubKeys { uint32_t k1a, k1b, k2a, k2b, k3a, k3b; };

static __device__ __forceinline__ SubKeys derive_keys() {
    uint32_t a0 = 0, b0 = 3; tf2x32(0u, 42u, a0, b0);
    uint32_t a1 = 1, b1 = 4; tf2x32(0u, 42u, a1, b1);
    uint32_t a2 = 2, b2 = 5; tf2x32(0u, 42u, a2, b2);
    SubKeys s; s.k1a = a0; s.k1b = a1; s.k2a = a2; s.k2b = b0; s.k3a = b1; s.k3b = b2;
    return s;
}

static __device__ __forceinline__ float bits_to_unit_float(uint32_t b) {
    return __uint_as_float((b >> 9) | 0x3f800000u) - 1.0f;
}

// generate the e-th tem pair slots (word0: index e, word1: index e+half)
struct TemPair { int r, c; };
static __device__ __forceinline__ void tem_pairs(int e, int half, float tf,
                                                 const int* __restrict__ mask_idx,
                                                 const SubKeys& sk,
                                                 TemPair& p0, TemPair& p1) {
    uint32_t u1a = (uint32_t)e, u1b = (uint32_t)(e + half);
    tf2x32(sk.k2a, sk.k2b, u1a, u1b);
    uint32_t u2a = (uint32_t)e, u2b = (uint32_t)(e + half);
    tf2x32(sk.k3a, sk.k3b, u2a, u2b);
    float a1 = bits_to_unit_float(u1a), a2 = bits_to_unit_float(u2a);
    float b1 = bits_to_unit_float(u1b), b2 = bits_to_unit_float(u2b);
    p0.r = mask_idx[(int)(a1 * tf)];   // floor==trunc for nonneg, f32 RN mul == jnp
    p0.c = mask_idx[(int)(a2 * tf)];
    p1.r = mask_idx[(int)(b1 * tf)];
    p1.c = mask_idx[(int)(b2 * tf)];
}

// ---------------- shared kernels ----------------
__global__ void k_seed(const int* __restrict__ seeds, int n_seeds,
                       unsigned char* __restrict__ seedm) {
    int i = blockIdx.x * blockDim.x + threadIdx.x;
    if (i < n_seeds) seedm[seeds[i]] = 1;
}

__global__ void k_edge1(const int* __restrict__ rows, const int* __restrict__ cols, int nnz,
                        const unsigned char* __restrict__ seedm,
                        unsigned char* __restrict__ keep, unsigned char* __restrict__ nxt) {
    int e = blockIdx.x * blockDim.x + threadIdx.x;
    if (e >= nnz) return;
    int r = rows[e], c = cols[e];
    bool inc = (seedm[r] | seedm[c]) != 0;
    keep[e] = inc ? 0 : 1;
    if (inc) { nxt[r] = 1; nxt[c] = 1; }   // same-value byte stores, race-safe
}

__global__ void k_edge2(const int* __restrict__ rows, const int* __restrict__ cols, int nnz,
                        const unsigned char* __restrict__ nxt,
                        unsigned char* __restrict__ keep) {
    int e = blockIdx.x * blockDim.x + threadIdx.x;
    if (e >= nnz) return;
    if (keep[e] && ((nxt[rows[e]] | nxt[cols[e]]) != 0)) keep[e] = 0;
}

__global__ void k_union(int n, const unsigned char* __restrict__ seedm,
                        const unsigned char* __restrict__ nxt,
                        unsigned char* __restrict__ mask) {
    int i = blockIdx.x * blockDim.x + threadIdx.x;
    if (i < n) mask[i] = (unsigned char)(seedm[i] | nxt[i]);
}

// samped = randint(k1,(samp_num,),0,N) with N=2^13 -> bits & (N-1).
__global__ void k_samp(int half, int modmask, unsigned char* __restrict__ mask) {
    int t = blockIdx.x * blockDim.x + threadIdx.x;
    if (t >= half) return;
    SubKeys sk = derive_keys();
    uint32_t x0 = (uint32_t)t, x1 = (uint32_t)(t + half);
    tf2x32(sk.k1a, sk.k1b, x0, x1);
    mask[x0 & (uint32_t)modmask] = 1;
    mask[x1 & (uint32_t)modmask] = 1;
}

// single-block scan: mask (n bytes, n<=8192) -> ascending mask_idx + tem_num
__global__ void __launch_bounds__(1024)
k_scan(int n, const unsigned char* __restrict__ mask,
       int* __restrict__ mask_idx, int* __restrict__ tem_num) {
    __shared__ int ssum[1024];
    int t = threadIdx.x;
    int per = n / 1024;           // 8 for n=8192
    int base = t * per;
    int loc[8];
    int s = 0;
    for (int j = 0; j < per; ++j) { loc[j] = mask[base + j]; s += loc[j]; }
    ssum[t] = s;
    __syncthreads();
    for (int off = 1; off < 1024; off <<= 1) {
        int v = (t >= off) ? ssum[t - off] : 0;
        __syncthreads();
        ssum[t] += v;
        __syncthreads();
    }
    int excl = ssum[t] - s;
    for (int j = 0; j < per; ++j)
        if (loc[j]) mask_idx[excl++] = base + j;
    if (t == 1023) *tem_num = ssum[1023];
}

__global__ void k_deg(const int* __restrict__ rows, const int* __restrict__ cols, int nnz,
                      const unsigned char* __restrict__ keep,
                      const float* __restrict__ comp, float* __restrict__ deg, int n) {
    int e = blockIdx.x * blockDim.x + threadIdx.x;
    if (e >= nnz) return;
    if (keep[e]) {
        int r = rows[e], c = cols[e];
        atomicAdd(&deg[r], comp[(size_t)r * n + c]);
    }
}

__global__ void k_norm(int n, const float* __restrict__ deg, float* __restrict__ nrm) {
    int i = blockIdx.x * blockDim.x + threadIdx.x;
    if (i < n) nrm[i] = 1.0f / sqrtf(deg[i] + 1e-12f);
}

// ---------------- fast path: per-row CSR coverage lists + dense fused write ----------------

__global__ void k_cnt_kept(const int* __restrict__ rows, int nnz,
                           const unsigned char* __restrict__ keep,
                           int* __restrict__ cnt_k) {
    int e = blockIdx.x * blockDim.x + threadIdx.x;
    if (e < nnz && keep[e]) atomicAdd(&cnt_k[rows[e]], 1);
}

__global__ void k_fill_kept(const int* __restrict__ rows, const int* __restrict__ cols,
                            int nnz, const unsigned char* __restrict__ keep,
                            int* __restrict__ cur_k, unsigned short* __restrict__ cols_k) {
    int e = blockIdx.x * blockDim.x + threadIdx.x;
    if (e < nnz && keep[e]) {
        int p = atomicAdd(&cur_k[rows[e]], 1);
        cols_k[p] = (unsigned short)cols[e];
    }
}

__global__ void k_cnt_tem(int half, const int* __restrict__ mask_idx,
                          const int* __restrict__ tem_num, int* __restrict__ cnt_t) {
    int e = blockIdx.x * blockDim.x + threadIdx.x;
    if (e >= half) return;
    SubKeys sk = derive_keys();
    float tf = (float)(*tem_num);
    TemPair p0, p1;
    tem_pairs(e, half, tf, mask_idx, sk, p0, p1);
    atomicAdd(&cnt_t[p0.r], 1); atomicAdd(&cnt_t[p0.c], 1);
    atomicAdd(&cnt_t[p1.r], 1); atomicAdd(&cnt_t[p1.c], 1);
}

__global__ void k_fill_tem(int half, const int* __restrict__ mask_idx,
                           const int* __restrict__ tem_num,
                           int* __restrict__ cur_t, unsigned short* __restrict__ cols_t) {
    int e = blockIdx.x * blockDim.x + threadIdx.x;
    if (e >= half) return;
    SubKeys sk = derive_keys();
    float tf = (float)(*tem_num);
    TemPair p0, p1;
    tem_pairs(e, half, tf, mask_idx, sk, p0, p1);
    int p;
    p = atomicAdd(&cur_t[p0.r], 1); cols_t[p] = (unsigned short)p0.c;
    p = atomicAdd(&cur_t[p0.c], 1); cols_t[p] = (unsigned short)p0.r;
    p = atomicAdd(&cur_t[p1.r], 1); cols_t[p] = (unsigned short)p1.c;
    p = atomicAdd(&cur_t[p1.c], 1); cols_t[p] = (unsigned short)p1.r;
}

// 2 blocks: block 0 scans cnt_k -> off_k/cur_k, block 1 scans cnt_t -> off_t/cur_t
__global__ void __launch_bounds__(1024)
k_scan_off(int n, const int* __restrict__ cnt_k, int* __restrict__ off_k, int* __restrict__ cur_k,
           const int* __restrict__ cnt_t, int* __restrict__ off_t, int* __restrict__ cur_t) {
    __shared__ int ssum[1024];
    const int* cnt = blockIdx.x ? cnt_t : cnt_k;
    int* off = blockIdx.x ? off_t : off_k;
    int* cur = blockIdx.x ? cur_t : cur_k;
    int t = threadIdx.x;
    int per = n / 1024;           // 8
    int base = t * per;
    int loc[8];
    int s = 0;
    for (int j = 0; j < per; ++j) { loc[j] = cnt[base + j]; s += loc[j]; }
    ssum[t] = s;
    __syncthreads();
    for (int o = 1; o < 1024; o <<= 1) {
        int v = (t >= o) ? ssum[t - o] : 0;
        __syncthreads();
        ssum[t] += v;
        __syncthreads();
    }
    int run = ssum[t] - s;        // exclusive prefix
    for (int j = 0; j < per; ++j) { off[base + j] = run; cur[base + j] = run; run += loc[j]; }
}

// one block per row, 256 threads. Rasterize coverage into LDS bitmaps, then
// stream the row out with coalesced nontemporal float4 stores.
__global__ void __launch_bounds__(256)
k_dense_lds(int n,
            const int* __restrict__ off_k, const int* __restrict__ cnt_k,
            const unsigned short* __restrict__ cols_k,
            const int* __restrict__ off_t, const int* __restrict__ cnt_t,
            const unsigned short* __restrict__ cols_t,
            const float* __restrict__ comp, const float* __restrict__ nrm,
            float* __restrict__ enc, float* __restrict__ dec) {
    __shared__ unsigned int se[256], sd[256];   // 8192 bits each
    int r = blockIdx.x;
    int t = threadIdx.x;
    se[t] = 0; sd[t] = 0;
    __syncthreads();
    int ok = off_k[r], ck = cnt_k[r];
    for (int i = t; i < ck; i += 256) {
        int c = cols_k[ok + i];
        unsigned int b = 1u << (c & 31);
        atomicOr(&se[c >> 5], b);
        atomicOr(&sd[c >> 5], b);
    }
    int ot = off_t[r], ct = cnt_t[r];
    for (int i = t; i < ct; i += 256) {
        int c = cols_t[ot + i];
        atomicOr(&sd[c >> 5], 1u << (c & 31));
    }
    if (t == 0) atomicOr(&sd[r >> 5], 1u << (r & 31));   // self loop
    __syncthreads();
    float nr = nrm[r];
    size_t rowo = (size_t)r * n;
    const f4* compv = (const f4*)(comp + rowo);
    const f4* nrmv  = (const f4*)nrm;
    f4* encv = (f4*)(enc + rowo);
    f4* decv = (f4*)(dec + rowo);
    int sh = (t & 7) * 4;                // nibble shift, constant over q
    int wb = t >> 3;
#pragma unroll
    for (int q = 0; q < 8; ++q) {        // 8192 floats / (4 * 256 threads) == 8
        int f = q * 256 + t;             // float4 index within row (coalesced)
        unsigned int ew = (se[q * 32 + wb] >> sh) & 0xFu;
        unsigned int dw = (sd[q * 32 + wb] >> sh) & 0xFu;
        f4 ev = {0.f, 0.f, 0.f, 0.f};
        f4 dv = {0.f, 0.f, 0.f, 0.f};
        if (ew | dw) {
            f4 cv = compv[f];
            if (dw & 1u) dv.x = cv.x;
            if (dw & 2u) dv.y = cv.y;
            if (dw & 4u) dv.z = cv.z;
            if (dw & 8u) dv.w = cv.w;
            if (ew) {
                f4 nv = nrmv[f];
                if (ew & 1u) ev.x = cv.x * nr * nv.x;
                if (ew & 2u) ev.y = cv.y * nr * nv.y;
                if (ew & 4u) ev.z = cv.z * nr * nv.z;
                if (ew & 8u) ev.w = cv.w * nr * nv.w;
            }
        }
        __builtin_nontemporal_store(ev, &encv[f]);
        __builtin_nontemporal_store(dv, &decv[f]);
    }
}

// ---------------- fallback path (previous verified kernels) ----------------
__global__ void k_enc(const int* __restrict__ rows, const int* __restrict__ cols, int nnz,
                      const unsigned char* __restrict__ keep,
                      const float* __restrict__ comp, const float* __restrict__ nrm,
                      float* __restrict__ enc, int n) {
    int e = blockIdx.x * blockDim.x + threadIdx.x;
    if (e >= nnz) return;
    if (keep[e]) {
        int r = rows[e], c = cols[e];
        size_t o = (size_t)r * n + c;
        enc[o] = comp[o] * nrm[r] * nrm[c];
    }
}

__global__ void k_dec_base(const int* __restrict__ rows, const int* __restrict__ cols,
                           int nnz, int n, const unsigned char* __restrict__ keep,
                           const float* __restrict__ comp, float* __restrict__ dec) {
    int e = blockIdx.x * blockDim.x + threadIdx.x;
    if (e < nnz) {
        if (keep[e]) {
            size_t o = (size_t)rows[e] * n + cols[e];
            dec[o] = comp[o];
        }
    } else if (e < nnz + n) {
        int i = e - nnz;
        size_t o = (size_t)i * n + i;
        dec[o] = comp[o];
    }
}

__global__ void k_dec_tem(int half, int n, const int* __restrict__ mask_idx,
                          const int* __restrict__ tem_num,
                          const float* __restrict__ comp, float* __restrict__ dec) {
    int e = blockIdx.x * blockDim.x + threadIdx.x;
    if (e >= half) return;
    SubKeys sk = derive_keys();
    float tf = (float)(*tem_num);
    TemPair p0, p1;
    tem_pairs(e, half, tf, mask_idx, sk, p0, p1);
    size_t o;
    o = (size_t)p0.r * n + p0.c; dec[o] = comp[o];
    o = (size_t)p0.c * n + p0.r; dec[o] = comp[o];
    o = (size_t)p1.r * n + p1.c; dec[o] = comp[o];
    o = (size_t)p1.c * n + p1.r; dec[o] = comp[o];
}

// ---------------- launch ----------------
extern "C" void kernel_launch(void* const* d_in, const int* in_sizes, int n_in,
                              void* d_out, int out_size, void* d_ws, size_t ws_size,
                              hipStream_t stream) {
    const int*   rows  = (const int*)d_in[0];
    const int*   cols  = (const int*)d_in[1];
    // d_in[2] = adj_values — unused by the forward
    const int*   seeds = (const int*)d_in[3];
    const float* comp  = (const float*)d_in[4];

    const int nnz     = in_sizes[0];
    const int n_seeds = in_sizes[3];
    const int n       = (int)(sqrt((double)in_sizes[4]) + 0.5);   // 8192

    float* enc = (float*)d_out;
    float* dec = enc + (size_t)n * n;

    // ---- small workspace region (same layout as previous verified kernel) ----
    char* ws = (char*)d_ws;
    float* deg            = (float*)(ws);
    float* nrm            = (float*)(ws + 4 * (size_t)n);
    int*   mask_idx       = (int*)  (ws + 8 * (size_t)n);
    int*   tem_num        = (int*)  (ws + 12 * (size_t)n);
    unsigned char* seedm  = (unsigned char*)(ws + 12 * (size_t)n + 256);
    unsigned char* nxt    = seedm + n;
    unsigned char* mask   = nxt + n;
    unsigned char* keep   = mask + n;   // nnz bytes, fully written each call

    size_t small_end = 12 * (size_t)n + 256 + 3 * (size_t)n + (size_t)nnz;
    size_t bko = (small_end + 255) & ~(size_t)255;

    // ---- CSR bucket region ----
    // cnt_k, cnt_t, off_k, cur_k, off_t, cur_t : 6 * 4n bytes
    // cols_k: nnz u16; cols_t: 2*nnz u16
    size_t bucket_end = bko + 24 * (size_t)n + 6 * (size_t)nnz;
    bool fast = (ws_size >= bucket_end) && (n == 8192);

    const int B = 256;
    int samp_num = (int)((double)n * 0.9);   // int(N*0.9) = 7372 (even)
    int shalf = samp_num / 2;
    int ehalf = nnz / 2;

    if (fast) {
        int* cnt_k = (int*)(ws + bko);
        int* cnt_t = (int*)(ws + bko + 4 * (size_t)n);
        int* off_k = (int*)(ws + bko + 8 * (size_t)n);
        int* cur_k = (int*)(ws + bko + 12 * (size_t)n);
        int* off_t = (int*)(ws + bko + 16 * (size_t)n);
        int* cur_t = (int*)(ws + bko + 20 * (size_t)n);
        unsigned short* cols_k = (unsigned short*)(ws + bko + 24 * (size_t)n);
        unsigned short* cols_t = cols_k + (size_t)nnz;

        // zero: small region + cnt arrays (~0.45 MB). NO d_out memset — k_dense_lds
        // writes every output byte exactly once.
        hipMemsetAsync(d_ws, 0, bko + 8 * (size_t)n, stream);

        k_seed <<<(n_seeds + B - 1) / B, B, 0, stream>>>(seeds, n_seeds, seedm);
        k_edge1<<<(nnz + B - 1) / B, B, 0, stream>>>(rows, cols, nnz, seedm, keep, nxt);
        k_edge2<<<(nnz + B - 1) / B, B, 0, stream>>>(rows, cols, nnz, nxt, keep);
        k_union<<<(n + B - 1) / B, B, 0, stream>>>(n, seedm, nxt, mask);
        k_samp <<<(shalf + B - 1) / B, B, 0, stream>>>(shalf, n - 1, mask);
        k_scan <<<1, 1024, 0, stream>>>(n, mask, mask_idx, tem_num);
        k_deg  <<<(nnz + B - 1) / B, B, 0, stream>>>(rows, cols, nnz, keep, comp, deg, n);
        k_norm <<<(n + B - 1) / B, B, 0, stream>>>(n, deg, nrm);

        k_cnt_kept<<<(nnz + B - 1) / B, B, 0, stream>>>(rows, nnz, keep, cnt_k);
        k_cnt_tem <<<(ehalf + B - 1) / B, B, 0, stream>>>(ehalf, mask_idx, tem_num, cnt_t);
        k_scan_off<<<2, 1024, 0, stream>>>(n, cnt_k, off_k, cur_k, cnt_t, off_t, cur_t);
        k_fill_kept<<<(nnz + B - 1) / B, B, 0, stream>>>(rows, cols, nnz, keep, cur_k, cols_k);
        k_fill_tem <<<(ehalf + B - 1) / B, B, 0, stream>>>(ehalf, mask_idx, tem_num, cur_t, cols_t);

        k_dense_lds<<<n, 256, 0, stream>>>(n, off_k, cnt_k, cols_k,
                                           off_t, cnt_t, cols_t,
                                           comp, nrm, enc, dec);
    } else {
        // previous verified path; memset exactly the 2*n*n floats the outputs
        // need (the old code wrote out_size*sizeof(float) = 4x too much: the
        // profile's 2 GiB / 335 us fillBufferAligned).
        size_t zbytes = 12 * (size_t)n + 256 + 3 * (size_t)n;
        hipMemsetAsync(d_ws, 0, zbytes, stream);
        hipMemsetAsync(d_out, 0, 2 * (size_t)n * (size_t)n * sizeof(float), stream);

        k_seed <<<(n_seeds + B - 1) / B, B, 0, stream>>>(seeds, n_seeds, seedm);
        k_edge1<<<(nnz + B - 1) / B, B, 0, stream>>>(rows, cols, nnz, seedm, keep, nxt);
        k_edge2<<<(nnz + B - 1) / B, B, 0, stream>>>(rows, cols, nnz, nxt, keep);
        k_union<<<(n + B - 1) / B, B, 0, stream>>>(n, seedm, nxt, mask);
        k_samp <<<(shalf + B - 1) / B, B, 0, stream>>>(shalf, n - 1, mask);
        k_scan <<<1, 1024, 0, stream>>>(n, mask, mask_idx, tem_num);
        k_deg  <<<(nnz + B - 1) / B, B, 0, stream>>>(rows, cols, nnz, keep, comp, deg, n);
        k_norm <<<(n + B - 1) / B, B, 0, stream>>>(n, deg, nrm);
        k_enc  <<<(nnz + B - 1) / B, B, 0, stream>>>(rows, cols, nnz, keep, comp, nrm, enc, n);
        k_dec_base<<<(nnz + n + B - 1) / B, B, 0, stream>>>(rows, cols, nnz, n, keep, comp, dec);
        k_dec_tem<<<(ehalf + B - 1) / B, B, 0, stream>>>(ehalf, n, mask_idx, tem_num, comp, dec);
    }
}